// Round 8
// baseline (178.484 us; speedup 1.0000x reference)
//
#include <hip/hip_runtime.h>
#include <hip/hip_bf16.h>
#include <stdint.h>

#define NROWS 16384
#define NDIM  1024
#define NLAB  64
#define NC    65
#define CPAD  80

typedef float float4v __attribute__((ext_vector_type(4)));
typedef short short8  __attribute__((ext_vector_type(8)));

// ---- workspace layout (bytes); nothing needs pre-zeroing ----
static constexpr size_t SCALE_B = 0;         // 80 f32 (w/||abf_c||)
static constexpr size_t ACTB_B  = 320;       // 80 u8 active flags
static constexpr size_t WSUM_B  = 400;       // f32 loss accumulator (zeroed by k2b)
static constexpr size_t CTR_B   = 404;       // u32 k3 completion counter (zeroed by k2b)
static constexpr size_t CNTF_B  = 448;       // 80 u32 counts (written by k2b)
static constexpr size_t CNTP_B  = 1024;      // 256 x 80 u32 per-block count slabs
static constexpr size_t MASK_B  = 83968;     // 16384 u64 row masks
static constexpr size_t XN2_B   = 215040;    // 16384 f32 row norms^2
static constexpr size_t LFRAG_B = 280576;    // labT bf16, A-frag layout (2.6 MB)
static constexpr size_t BFRAG_B = 2902016;   // unit anchors bf16, B-frag layout
static constexpr size_t XAF_B   = 3065856;   // x bf16, A-frag layout (32 MB)
static constexpr size_t XCOL_B  = 36620288;  // x bf16, col-major 16-row tiles (32 MB)
static constexpr size_t PART_B  = 70174720;  // kslices*80*1024 f32 partials
static constexpr size_t SLAB    = (size_t)CPAD * NDIM * 4;

__device__ __forceinline__ unsigned short bf16u(float f) {
    __hip_bfloat16 h = __float2bfloat16(f);
    return __builtin_bit_cast(unsigned short, h);
}
__device__ __forceinline__ unsigned pk2(float a, float b) {
    return (unsigned)bf16u(a) | ((unsigned)bf16u(b) << 16);
}

// ---- K01: blocks 0..1023 = x prep (xAfrag/xcol/xn2); 1024..1279 = labels ----
__global__ __launch_bounds__(256) void k01_prep(const float* __restrict__ x,
                                                const int* __restrict__ label,
                                                unsigned short* __restrict__ xAfrag,
                                                unsigned short* __restrict__ xcol,
                                                float* __restrict__ xn2g,
                                                unsigned long long* __restrict__ masks,
                                                unsigned* __restrict__ cntpart,
                                                unsigned short* __restrict__ lfrag) {
    __shared__ unsigned short xt[16][1034];
    __shared__ unsigned cnt[NC];
    __shared__ unsigned long long smask[64];
    int t = threadIdx.x;
    if (blockIdx.x < 1024) {
        int rt = blockIdx.x;
        int r = t >> 4, cpos = t & 15;
        const float* src = x + ((size_t)rt * 16 + r) * NDIM + cpos * 4;
        float sq = 0.f;
#pragma unroll
        for (int i = 0; i < 16; ++i) {
            float4 f = *(const float4*)(src + i * 64);
            sq += f.x * f.x + f.y * f.y + f.z * f.z + f.w * f.w;
            *(uint2*)&xt[r][cpos * 4 + i * 64] = make_uint2(pk2(f.x, f.y), pk2(f.z, f.w));
        }
#pragma unroll
        for (int m = 1; m < 16; m <<= 1) sq += __shfl_xor(sq, m, 16);
        if (cpos == 0) xn2g[rt * 16 + r] = sq;
        __syncthreads();
        {
            int slot = t & 63, wv = t >> 6;
            int q = slot >> 4, col = slot & 15;
#pragma unroll
            for (int s = 0; s < 8; ++s) {
                int kb = s * 4 + wv;
                uint4 v = *(const uint4*)&xt[col][kb * 32 + q * 8];
                ((uint4*)xAfrag)[((size_t)rt * 32 + kb) * 64 + slot] = v;
            }
        }
#pragma unroll
        for (int s = 0; s < 8; ++s) {
            int dim = s * 128 + (t >> 1);
            int rh = (t & 1) * 8;
            unsigned short tmp[8];
#pragma unroll
            for (int j = 0; j < 8; ++j) tmp[j] = xt[rh + j][dim];
            uint4 v;
            v.x = (unsigned)tmp[0] | ((unsigned)tmp[1] << 16);
            v.y = (unsigned)tmp[2] | ((unsigned)tmp[3] << 16);
            v.z = (unsigned)tmp[4] | ((unsigned)tmp[5] << 16);
            v.w = (unsigned)tmp[6] | ((unsigned)tmp[7] << 16);
            ((uint4*)xcol)[(size_t)rt * 2048 + s * 256 + t] = v;
        }
        return;
    }
    // ---- label path ----
    int bid = blockIdx.x - 1024;
    if (t < NC) cnt[t] = 0;
    __syncthreads();
    int wave = t >> 6, lane = t & 63;
    int rowblock = bid * 64;
    unsigned creg = 0, zreg = 0;
#pragma unroll 4
    for (int p = 0; p < 16; ++p) {
        int row = rowblock + p * 4 + wave;
        int v = label[row * NLAB + lane];
        unsigned long long m = __ballot(v != 0);
        creg += (unsigned)((m >> lane) & 1ull);
        if (lane == 0) {
            masks[row] = m;
            smask[p * 4 + wave] = m;
            zreg += (m == 0ull) ? 1u : 0u;
        }
    }
    atomicAdd(&cnt[lane], creg);
    if (lane == 0 && zreg) atomicAdd(&cnt[64], zreg);
    __syncthreads();
    if (t < 80) cntpart[bid * 80 + t] = (t < NC) ? cnt[t] : 0u;
    for (int pid = t; pid < 640; pid += 256) {
        int rt2l = pid / 320, rem = pid % 320;
        int ct = rem >> 6, ln = rem & 63;
        int q = ln >> 4, col = ln & 15;
        int c = ct * 16 + col;
        int rbase = rt2l * 32 + q * 8;
        unsigned pk[4];
#pragma unroll
        for (int jp = 0; jp < 4; ++jp) {
            unsigned long long m0 = smask[rbase + jp * 2], m1 = smask[rbase + jp * 2 + 1];
            unsigned b0, b1;
            if (c < 64)       { b0 = (unsigned)((m0 >> c) & 1ull); b1 = (unsigned)((m1 >> c) & 1ull); }
            else if (c == 64) { b0 = (m0 == 0ull); b1 = (m1 == 0ull); }
            else              { b0 = 0u; b1 = 0u; }
            pk[jp] = (b0 ? 0x3F80u : 0u) | (b1 ? 0x3F800000u : 0u);
        }
        uint4 w = make_uint4(pk[0], pk[1], pk[2], pk[3]);
        ((uint4*)lfrag)[((size_t)(bid * 2 + rt2l) * 5 + ct) * 64 + ln] = w;
    }
}

// ---- K2: sums = labT @ x; all-contiguous frag loads, barrier-free ----
__global__ __launch_bounds__(256, 4) void k2_sums(const unsigned short* __restrict__ xcol,
                                                  const unsigned short* __restrict__ lfrag,
                                                  float* __restrict__ partial,
                                                  int kslices) {
    int t = threadIdx.x, wave = t >> 6, lane = t & 63;
    int q = lane >> 4, col = lane & 15;
    int dgroup = blockIdx.x & 15, ks = blockIdx.x >> 4;
    int nkb = (NROWS / kslices) >> 5;
    int kb0 = ks * nkb;
    int d = dgroup * 64 + wave * 16 + col;
    const uint4* B = (const uint4*)xcol;
    const uint4* A = (const uint4*)lfrag;
    size_t bidx0 = (size_t)d * 2 + (q & 1);
    int qh = q >> 1;

    float4v acc[5];
#pragma unroll
    for (int ct = 0; ct < 5; ++ct) acc[ct] = (float4v){0.f, 0.f, 0.f, 0.f};

#pragma unroll 4
    for (int i = 0; i < nkb; ++i) {
        int kb = kb0 + i;
        uint4 braw = B[(size_t)(kb * 2 + qh) * 2048 + bidx0];
        short8 bf = __builtin_bit_cast(short8, braw);
#pragma unroll
        for (int ct = 0; ct < 5; ++ct) {
            uint4 araw = A[((size_t)kb * 5 + ct) * 64 + lane];
            short8 af = __builtin_bit_cast(short8, araw);
            acc[ct] = __builtin_amdgcn_mfma_f32_16x16x32_bf16(af, bf, acc[ct], 0, 0, 0);
        }
    }
    float* pb = partial + (size_t)ks * CPAD * NDIM;
#pragma unroll
    for (int ct = 0; ct < 5; ++ct)
#pragma unroll
        for (int reg = 0; reg < 4; ++reg)
            pb[(size_t)(ct * 16 + q * 4 + reg) * NDIM + d] = acc[ct][reg];
}

// ---- K2b: counts from cntpart; reduce slabs -> unit anchors (B-frag) + scale;
// also zeroes wsum/counter for k3. ----
__global__ __launch_bounds__(256) void k2b_fuse(const float* __restrict__ wptr,
                                                const unsigned* __restrict__ cntpart,
                                                const float* __restrict__ partial,
                                                int kslices,
                                                unsigned short* __restrict__ bfrag,
                                                float* __restrict__ scale,
                                                unsigned char* __restrict__ actB,
                                                unsigned* __restrict__ countsF,
                                                float* __restrict__ wsum,
                                                unsigned* __restrict__ counter) {
    int c = blockIdx.x, t = threadIdx.x;
    __shared__ float red[8];
    __shared__ unsigned credu[4];
    if (c == 0 && t == 1) { *wsum = 0.f; *counter = 0u; }
    unsigned cv = cntpart[t * 80 + c];
#pragma unroll
    for (int m = 32; m >= 1; m >>= 1) cv += __shfl_xor(cv, m, 64);
    if ((t & 63) == 0) credu[t >> 6] = cv;
    __syncthreads();
    unsigned cnt = credu[0] + credu[1] + credu[2] + credu[3];

    int d0 = t * 4;
    const float* p = partial + (size_t)c * NDIM + d0;
    float4 s = make_float4(0.f, 0.f, 0.f, 0.f);
#pragma unroll 8
    for (int sl = 0; sl < kslices; ++sl) {
        float4 v = *(const float4*)(p + (size_t)sl * CPAD * NDIM);
        s.x += v.x; s.y += v.y; s.z += v.z; s.w += v.w;
    }
    float invc = 1.0f / (float)(cnt > 0u ? cnt : 1u);
    float ax = s.x * invc, ay = s.y * invc, az = s.z * invc, aw = s.w * invc;
    float ss = ax * ax + ay * ay + az * az + aw * aw;
#pragma unroll
    for (int m = 32; m >= 1; m >>= 1) ss += __shfl_xor(ss, m, 64);
    if ((t & 63) == 0) red[t >> 6] = ss;
    __syncthreads();
    ss = red[0] + red[1] + red[2] + red[3];

    float denom = fmaxf(sqrtf(ss), 1e-8f);   // an = max(||anchor||, eps)
    float rinv = invc / denom;
    unsigned short h0 = bf16u(s.x * rinv), h1 = bf16u(s.y * rinv);
    unsigned short h2 = bf16u(s.z * rinv), h3 = bf16u(s.w * rinv);
    // B-frag slot: chunk (ct, kb), lane (q, colc), elems j
    int ct = c >> 4, colc = c & 15;
    int kb = d0 >> 5, q = (d0 >> 3) & 3, j0 = d0 & 7;
    size_t sidx = ((((size_t)ct * 32 + kb) * 64) + q * 16 + colc) * 8 + j0;
    *(uint2*)(bfrag + sidx) =
        make_uint2(((unsigned)h1 << 16) | h0, ((unsigned)h3 << 16) | h2);

    float f0 = __bfloat162float(__builtin_bit_cast(__hip_bfloat16, h0));
    float f1 = __bfloat162float(__builtin_bit_cast(__hip_bfloat16, h1));
    float f2 = __bfloat162float(__builtin_bit_cast(__hip_bfloat16, h2));
    float f3 = __bfloat162float(__builtin_bit_cast(__hip_bfloat16, h3));
    float nb2 = f0 * f0 + f1 * f1 + f2 * f2 + f3 * f3;
#pragma unroll
    for (int m = 32; m >= 1; m >>= 1) nb2 += __shfl_xor(nb2, m, 64);
    if ((t & 63) == 0) red[4 + (t >> 6)] = nb2;
    __syncthreads();
    if (t == 0) {
        float n2 = red[4] + red[5] + red[6] + red[7];
        scale[c] = (n2 > 0.f) ? (wptr[0] / sqrtf(n2)) : 0.f;
        actB[c] = (cnt > 0u) ? 1 : 0;
        countsF[c] = cnt;
    }
}

// ---- K3: cos GEMM + fused softmax loss; last block finalizes the output ----
__global__ __launch_bounds__(256, 4) void k3_loss(const unsigned short* __restrict__ xAfrag,
                                                  const unsigned short* __restrict__ bfrag,
                                                  const float* __restrict__ xn2g,
                                                  const unsigned long long* __restrict__ masks,
                                                  const unsigned char* __restrict__ actB,
                                                  const float* __restrict__ scale,
                                                  const unsigned* __restrict__ countsF,
                                                  const float* __restrict__ bptr,
                                                  float* __restrict__ wsum,
                                                  unsigned* __restrict__ counter,
                                                  float* __restrict__ out) {
    __shared__ float xch[3][64 * 20];
    int t = threadIdx.x, kh = t >> 6, lane = t & 63;
    int q = lane >> 4, col = lane & 15;
    int rt = blockIdx.x;
    int rowbase = rt * 16;
    const uint4* A = (const uint4*)xAfrag;
    const uint4* B = (const uint4*)bfrag;

    float4v acc[5];
#pragma unroll
    for (int ct = 0; ct < 5; ++ct) acc[ct] = (float4v){0.f, 0.f, 0.f, 0.f};

#pragma unroll
    for (int s = 0; s < 8; ++s) {
        int kb = kh * 8 + s;
        uint4 araw = A[((size_t)rt * 32 + kb) * 64 + lane];
        short8 af = __builtin_bit_cast(short8, araw);
#pragma unroll
        for (int ct = 0; ct < 5; ++ct) {
            uint4 braw = B[((size_t)ct * 32 + kb) * 64 + lane];
            short8 bf = __builtin_bit_cast(short8, braw);
            acc[ct] = __builtin_amdgcn_mfma_f32_16x16x32_bf16(af, bf, acc[ct], 0, 0, 0);
        }
    }
    if (kh) {
        float* dst = &xch[kh - 1][lane * 20];
#pragma unroll
        for (int ct = 0; ct < 5; ++ct)
#pragma unroll
            for (int r = 0; r < 4; ++r) dst[ct * 4 + r] = acc[ct][r];
    }
    __syncthreads();
    if (kh) return;
#pragma unroll
    for (int j = 0; j < 3; ++j) {
        const float* src = &xch[j][lane * 20];
#pragma unroll
        for (int ct = 0; ct < 5; ++ct)
#pragma unroll
            for (int r = 0; r < 4; ++r) acc[ct][r] += src[ct * 4 + r];
    }

    float bv = bptr[0];
    float sc[5]; unsigned char ab[5];
#pragma unroll
    for (int ct = 0; ct < 5; ++ct) { sc[ct] = scale[ct * 16 + col]; ab[ct] = actB[ct * 16 + col]; }

    float contrib = 0.f;
#pragma unroll
    for (int reg = 0; reg < 4; ++reg) {
        int rl = q * 4 + reg;
        int row = rowbase + rl;
        float inv = 1.0f / fmaxf(sqrtf(xn2g[row]), 1e-8f);
        unsigned long long mask = masks[row];
        float v[5]; float lmax = -1e30f;
#pragma unroll
        for (int ct = 0; ct < 5; ++ct) {
            float lg = acc[ct][reg] * sc[ct] * inv + bv;   // w*cos + b
            v[ct] = ab[ct] ? lg : -1e30f;
            lmax = fmaxf(lmax, v[ct]);
        }
#pragma unroll
        for (int m = 1; m < 16; m <<= 1) lmax = fmaxf(lmax, __shfl_xor(lmax, m, 16));
        float es = 0.f;
#pragma unroll
        for (int ct = 0; ct < 5; ++ct) es += expf(v[ct] - lmax);
#pragma unroll
        for (int m = 1; m < 16; m <<= 1) es += __shfl_xor(es, m, 16);
        float lse = lmax + logf(es);
        float ps = 0.f;
#pragma unroll
        for (int ct = 0; ct < 5; ++ct) {
            int c = ct * 16 + col;
            bool pos = (c < 64) ? (((mask >> c) & 1ull) != 0ull)
                                : ((c == 64) ? (mask == 0ull) : false);
            ps += pos ? v[ct] : 0.f;
        }
#pragma unroll
        for (int m = 1; m < 16; m <<= 1) ps += __shfl_xor(ps, m, 16);
        float npos = mask ? (float)__popcll(mask) : 1.0f;
        float crow = ps - npos * lse;
        if (col == 0) contrib += crow;
    }
#pragma unroll
    for (int m = 1; m < 64; m <<= 1) contrib += __shfl_xor(contrib, m, 64);
    if (lane == 0) {
        atomicAdd(wsum, contrib);
        __threadfence();
        unsigned old = atomicAdd(counter, 1u);
        if (old == (unsigned)gridDim.x - 1u) {
            float np = 0.f;
            for (int c = 0; c < NC; ++c) np += (float)countsF[c];
            float tot = atomicAdd(wsum, 0.0f);   // coherent read of the full sum
            out[0] = -tot / np;
        }
    }
}

extern "C" void kernel_launch(void* const* d_in, const int* in_sizes, int n_in,
                              void* d_out, int out_size, void* d_ws, size_t ws_size,
                              hipStream_t stream) {
    (void)in_sizes; (void)n_in; (void)out_size;
    const float* x = (const float*)d_in[0];
    const int* label = (const int*)d_in[1];
    const float* w = (const float*)d_in[2];
    const float* b = (const float*)d_in[3];

    char* ws = (char*)d_ws;
    float* scale = (float*)(ws + SCALE_B);
    unsigned char* actB = (unsigned char*)(ws + ACTB_B);
    float* wsum = (float*)(ws + WSUM_B);
    unsigned* counter = (unsigned*)(ws + CTR_B);
    unsigned* countsF = (unsigned*)(ws + CNTF_B);
    unsigned* cntpart = (unsigned*)(ws + CNTP_B);
    unsigned long long* masks = (unsigned long long*)(ws + MASK_B);
    float* xn2g = (float*)(ws + XN2_B);
    unsigned short* lfrag = (unsigned short*)(ws + LFRAG_B);
    unsigned short* bfrag = (unsigned short*)(ws + BFRAG_B);
    unsigned short* xAfrag = (unsigned short*)(ws + XAF_B);
    unsigned short* xcol = (unsigned short*)(ws + XCOL_B);
    float* partial = (float*)(ws + PART_B);

    int kslices = 64;
    while (kslices > 8 && PART_B + (size_t)kslices * SLAB > ws_size) kslices >>= 1;

    hipLaunchKernelGGL(k01_prep, dim3(1024 + 256), dim3(256), 0, stream,
                       x, label, xAfrag, xcol, xn2g, masks, cntpart, lfrag);
    hipLaunchKernelGGL(k2_sums, dim3(16 * kslices), dim3(256), 0, stream,
                       xcol, lfrag, partial, kslices);
    hipLaunchKernelGGL(k2b_fuse, dim3(CPAD), dim3(256), 0, stream,
                       w, cntpart, partial, kslices, bfrag, scale, actB, countsF, wsum, counter);
    hipLaunchKernelGGL(k3_loss, dim3(NROWS / 16), dim3(256), 0, stream,
                       xAfrag, bfrag, xn2g, masks, actB, scale, countsF, b, wsum, counter,
                       (float*)d_out);
}

// Round 9
// 161.638 us; speedup vs baseline: 1.1042x; 1.1042x over previous
//
#include <hip/hip_runtime.h>
#include <hip/hip_bf16.h>
#include <stdint.h>

#define NROWS 16384
#define NDIM  1024
#define NLAB  64
#define NC    65
#define CPAD  80

typedef float float4v __attribute__((ext_vector_type(4)));
typedef short short8  __attribute__((ext_vector_type(8)));

// ---- workspace layout (bytes); nothing needs pre-zeroing ----
static constexpr size_t SCALE_B = 0;         // 80 f32 (w/||abf_c||)
static constexpr size_t ACTB_B  = 320;       // 80 u8 active flags
static constexpr size_t WSUM_B  = 400;       // f32 loss accumulator (zeroed by k2b)
static constexpr size_t CNTF_B  = 448;       // 80 u32 counts (written by k2b)
static constexpr size_t CNTP_B  = 1024;      // 256 x 80 u32 per-block count slabs
static constexpr size_t MASK_B  = 83968;     // 16384 u64 row masks
static constexpr size_t XN2_B   = 215040;    // 16384 f32 row norms^2
static constexpr size_t LFRAG_B = 280576;    // labT bf16, A-frag layout (2.6 MB)
static constexpr size_t BFRAG_B = 2902016;   // unit anchors bf16, B-frag layout
static constexpr size_t XAF_B   = 3065856;   // x bf16, A-frag layout (32 MB)
static constexpr size_t XCOL_B  = 36620288;  // x bf16, col-major 16-row tiles (32 MB)
static constexpr size_t PART_B  = 70174720;  // kslices*80*1024 f32 partials
static constexpr size_t SLAB    = (size_t)CPAD * NDIM * 4;

__device__ __forceinline__ unsigned short bf16u(float f) {
    __hip_bfloat16 h = __float2bfloat16(f);
    return __builtin_bit_cast(unsigned short, h);
}
__device__ __forceinline__ unsigned pk2(float a, float b) {
    return (unsigned)bf16u(a) | ((unsigned)bf16u(b) << 16);
}

// ---- K01: blocks 0..1023 = x prep (xAfrag/xcol/xn2); 1024..1279 = labels ----
__global__ __launch_bounds__(256) void k01_prep(const float* __restrict__ x,
                                                const int* __restrict__ label,
                                                unsigned short* __restrict__ xAfrag,
                                                unsigned short* __restrict__ xcol,
                                                float* __restrict__ xn2g,
                                                unsigned long long* __restrict__ masks,
                                                unsigned* __restrict__ cntpart,
                                                unsigned short* __restrict__ lfrag) {
    __shared__ unsigned short xt[16][1034];
    __shared__ unsigned cnt[NC];
    __shared__ unsigned long long smask[64];
    int t = threadIdx.x;
    if (blockIdx.x < 1024) {
        int rt = blockIdx.x;
        int r = t >> 4, cpos = t & 15;
        const float* src = x + ((size_t)rt * 16 + r) * NDIM + cpos * 4;
        float sq = 0.f;
#pragma unroll
        for (int i = 0; i < 16; ++i) {
            float4 f = *(const float4*)(src + i * 64);
            sq += f.x * f.x + f.y * f.y + f.z * f.z + f.w * f.w;
            *(uint2*)&xt[r][cpos * 4 + i * 64] = make_uint2(pk2(f.x, f.y), pk2(f.z, f.w));
        }
#pragma unroll
        for (int m = 1; m < 16; m <<= 1) sq += __shfl_xor(sq, m, 16);
        if (cpos == 0) xn2g[rt * 16 + r] = sq;
        __syncthreads();
        {
            int slot = t & 63, wv = t >> 6;
            int q = slot >> 4, col = slot & 15;
#pragma unroll
            for (int s = 0; s < 8; ++s) {
                int kb = s * 4 + wv;
                uint4 v = *(const uint4*)&xt[col][kb * 32 + q * 8];
                ((uint4*)xAfrag)[((size_t)rt * 32 + kb) * 64 + slot] = v;
            }
        }
#pragma unroll
        for (int s = 0; s < 8; ++s) {
            int dim = s * 128 + (t >> 1);
            int rh = (t & 1) * 8;
            unsigned short tmp[8];
#pragma unroll
            for (int j = 0; j < 8; ++j) tmp[j] = xt[rh + j][dim];
            uint4 v;
            v.x = (unsigned)tmp[0] | ((unsigned)tmp[1] << 16);
            v.y = (unsigned)tmp[2] | ((unsigned)tmp[3] << 16);
            v.z = (unsigned)tmp[4] | ((unsigned)tmp[5] << 16);
            v.w = (unsigned)tmp[6] | ((unsigned)tmp[7] << 16);
            ((uint4*)xcol)[(size_t)rt * 2048 + s * 256 + t] = v;
        }
        return;
    }
    // ---- label path ----
    int bid = blockIdx.x - 1024;
    if (t < NC) cnt[t] = 0;
    __syncthreads();
    int wave = t >> 6, lane = t & 63;
    int rowblock = bid * 64;
    unsigned creg = 0, zreg = 0;
#pragma unroll 4
    for (int p = 0; p < 16; ++p) {
        int row = rowblock + p * 4 + wave;
        int v = label[row * NLAB + lane];
        unsigned long long m = __ballot(v != 0);
        creg += (unsigned)((m >> lane) & 1ull);
        if (lane == 0) {
            masks[row] = m;
            smask[p * 4 + wave] = m;
            zreg += (m == 0ull) ? 1u : 0u;
        }
    }
    atomicAdd(&cnt[lane], creg);
    if (lane == 0 && zreg) atomicAdd(&cnt[64], zreg);
    __syncthreads();
    if (t < 80) cntpart[bid * 80 + t] = (t < NC) ? cnt[t] : 0u;
    for (int pid = t; pid < 640; pid += 256) {
        int rt2l = pid / 320, rem = pid % 320;
        int ct = rem >> 6, ln = rem & 63;
        int q = ln >> 4, col = ln & 15;
        int c = ct * 16 + col;
        int rbase = rt2l * 32 + q * 8;
        unsigned pk[4];
#pragma unroll
        for (int jp = 0; jp < 4; ++jp) {
            unsigned long long m0 = smask[rbase + jp * 2], m1 = smask[rbase + jp * 2 + 1];
            unsigned b0, b1;
            if (c < 64)       { b0 = (unsigned)((m0 >> c) & 1ull); b1 = (unsigned)((m1 >> c) & 1ull); }
            else if (c == 64) { b0 = (m0 == 0ull); b1 = (m1 == 0ull); }
            else              { b0 = 0u; b1 = 0u; }
            pk[jp] = (b0 ? 0x3F80u : 0u) | (b1 ? 0x3F800000u : 0u);
        }
        uint4 w = make_uint4(pk[0], pk[1], pk[2], pk[3]);
        ((uint4*)lfrag)[((size_t)(bid * 2 + rt2l) * 5 + ct) * 64 + ln] = w;
    }
}

// ---- K2: sums = labT @ x; explicit 2-set ping-pong pipeline, barrier-free ----
__global__ __launch_bounds__(256) void k2_sums(const unsigned short* __restrict__ xcol,
                                               const unsigned short* __restrict__ lfrag,
                                               float* __restrict__ partial,
                                               int kslices) {
    int t = threadIdx.x, wave = t >> 6, lane = t & 63;
    int q = lane >> 4, col = lane & 15;
    int dgroup = blockIdx.x & 15, ks = blockIdx.x >> 4;
    int nkb = (NROWS / kslices) >> 5;
    int kb0 = ks * nkb;
    int d = dgroup * 64 + wave * 16 + col;
    const uint4* B = (const uint4*)xcol;
    const uint4* A = (const uint4*)lfrag;
    size_t bidx0 = (size_t)d * 2 + (q & 1);
    int qh = q >> 1;

    float4v acc[5];
#pragma unroll
    for (int ct = 0; ct < 5; ++ct) acc[ct] = (float4v){0.f, 0.f, 0.f, 0.f};

    uint4 b0 = B[(size_t)((kb0 + 0) * 2 + qh) * 2048 + bidx0];
    uint4 a0[5];
#pragma unroll
    for (int ct = 0; ct < 5; ++ct) a0[ct] = A[((size_t)(kb0 + 0) * 5 + ct) * 64 + lane];
    uint4 b1 = B[(size_t)((kb0 + 1) * 2 + qh) * 2048 + bidx0];
    uint4 a1[5];
#pragma unroll
    for (int ct = 0; ct < 5; ++ct) a1[ct] = A[((size_t)(kb0 + 1) * 5 + ct) * 64 + lane];

    for (int i = 0; i < nkb; i += 2) {
        int p2 = i + 2 < nkb ? kb0 + i + 2 : kb0 + i;
        int p3 = i + 3 < nkb ? kb0 + i + 3 : kb0 + i + 1;
        {
            short8 bf = __builtin_bit_cast(short8, b0);
#pragma unroll
            for (int ct = 0; ct < 5; ++ct) {
                short8 af = __builtin_bit_cast(short8, a0[ct]);
                acc[ct] = __builtin_amdgcn_mfma_f32_16x16x32_bf16(af, bf, acc[ct], 0, 0, 0);
            }
            b0 = B[(size_t)(p2 * 2 + qh) * 2048 + bidx0];
#pragma unroll
            for (int ct = 0; ct < 5; ++ct) a0[ct] = A[((size_t)p2 * 5 + ct) * 64 + lane];
        }
        {
            short8 bf = __builtin_bit_cast(short8, b1);
#pragma unroll
            for (int ct = 0; ct < 5; ++ct) {
                short8 af = __builtin_bit_cast(short8, a1[ct]);
                acc[ct] = __builtin_amdgcn_mfma_f32_16x16x32_bf16(af, bf, acc[ct], 0, 0, 0);
            }
            b1 = B[(size_t)(p3 * 2 + qh) * 2048 + bidx0];
#pragma unroll
            for (int ct = 0; ct < 5; ++ct) a1[ct] = A[((size_t)p3 * 5 + ct) * 64 + lane];
        }
    }
    float* pb = partial + (size_t)ks * CPAD * NDIM;
#pragma unroll
    for (int ct = 0; ct < 5; ++ct)
#pragma unroll
        for (int reg = 0; reg < 4; ++reg)
            pb[(size_t)(ct * 16 + q * 4 + reg) * NDIM + d] = acc[ct][reg];
}

// ---- K2b: 80 blocks x 1024 thr; counts + slab reduce + unit anchors (B-frag) ----
__global__ __launch_bounds__(1024) void k2b_fuse(const float* __restrict__ wptr,
                                                 const unsigned* __restrict__ cntpart,
                                                 const float* __restrict__ partial,
                                                 int kslices,
                                                 unsigned short* __restrict__ bfrag,
                                                 float* __restrict__ scale,
                                                 unsigned char* __restrict__ actB,
                                                 unsigned* __restrict__ countsF,
                                                 float* __restrict__ wsum) {
    int c = blockIdx.x, t = threadIdx.x;
    __shared__ float red[16];
    __shared__ unsigned credu[4];
    __shared__ float bcast[2];
    if (c == 0 && t == 512) *wsum = 0.f;
    if (t < 256) {
        unsigned cv = cntpart[t * 80 + c];
#pragma unroll
        for (int m = 32; m >= 1; m >>= 1) cv += __shfl_xor(cv, m, 64);
        if ((t & 63) == 0) credu[t >> 6] = cv;
    }
    __syncthreads();
    unsigned cnt = credu[0] + credu[1] + credu[2] + credu[3];

    const float* p = partial + (size_t)c * NDIM + t;
    float s = 0.f;
#pragma unroll 8
    for (int sl = 0; sl < kslices; ++sl)
        s += p[(size_t)sl * CPAD * NDIM];
    float invc = 1.0f / (float)(cnt > 0u ? cnt : 1u);
    float a = s * invc;
    float ss = a * a;
#pragma unroll
    for (int m = 32; m >= 1; m >>= 1) ss += __shfl_xor(ss, m, 64);
    if ((t & 63) == 0) red[t >> 6] = ss;
    __syncthreads();
    if (t == 0) {
        float tot = 0.f;
#pragma unroll
        for (int j = 0; j < 16; ++j) tot += red[j];
        bcast[0] = fmaxf(sqrtf(tot), 1e-8f);   // an = max(||anchor||, eps)
    }
    __syncthreads();
    float rinv = 1.0f / bcast[0];
    unsigned short h = bf16u(a * rinv);
    // B-frag slot for (c, d=t)
    int ct = c >> 4, colc = c & 15;
    int kb = t >> 5, q = (t >> 3) & 3, j0 = t & 7;
    bfrag[((((size_t)ct * 32 + kb) * 64) + q * 16 + colc) * 8 + j0] = h;
    float hv = __bfloat162float(__builtin_bit_cast(__hip_bfloat16, h));
    float nb2 = hv * hv;
#pragma unroll
    for (int m = 32; m >= 1; m >>= 1) nb2 += __shfl_xor(nb2, m, 64);
    if ((t & 63) == 0) red[t >> 6] = nb2;
    __syncthreads();
    if (t == 0) {
        float n2 = 0.f;
#pragma unroll
        for (int j = 0; j < 16; ++j) n2 += red[j];
        scale[c] = (n2 > 0.f) ? (wptr[0] / sqrtf(n2)) : 0.f;
        actB[c] = (cnt > 0u) ? 1 : 0;
        countsF[c] = cnt;
    }
}

// ---- K3: cos GEMM; wave = one 16-row tile, full K, ping-pong pipeline,
// no LDS / no barriers; per-wave fused softmax loss ----
__global__ __launch_bounds__(256) void k3_loss(const unsigned short* __restrict__ xAfrag,
                                               const unsigned short* __restrict__ bfrag,
                                               const float* __restrict__ xn2g,
                                               const unsigned long long* __restrict__ masks,
                                               const unsigned char* __restrict__ actB,
                                               const float* __restrict__ scale,
                                               const float* __restrict__ bptr,
                                               float* __restrict__ wsum) {
    int t = threadIdx.x, wave = t >> 6, lane = t & 63;
    int q = lane >> 4, col = lane & 15;
    int rt = blockIdx.x * 4 + wave;
    int rowbase = rt * 16;
    const uint4* A = (const uint4*)xAfrag + (size_t)rt * 32 * 64 + lane;
    const uint4* Bp = (const uint4*)bfrag + lane;

    float4v acc[5];
#pragma unroll
    for (int ct = 0; ct < 5; ++ct) acc[ct] = (float4v){0.f, 0.f, 0.f, 0.f};

    uint4 a0 = A[0], a1 = A[64];
    uint4 b0[5], b1[5];
#pragma unroll
    for (int ct = 0; ct < 5; ++ct) b0[ct] = Bp[(size_t)(ct * 32 + 0) * 64];
#pragma unroll
    for (int ct = 0; ct < 5; ++ct) b1[ct] = Bp[(size_t)(ct * 32 + 1) * 64];

    for (int s = 0; s < 32; s += 2) {
        int p2 = s + 2 < 32 ? s + 2 : s;
        int p3 = s + 3 < 32 ? s + 3 : s + 1;
        {
            short8 af = __builtin_bit_cast(short8, a0);
#pragma unroll
            for (int ct = 0; ct < 5; ++ct) {
                short8 bf = __builtin_bit_cast(short8, b0[ct]);
                acc[ct] = __builtin_amdgcn_mfma_f32_16x16x32_bf16(af, bf, acc[ct], 0, 0, 0);
            }
            a0 = A[p2 * 64];
#pragma unroll
            for (int ct = 0; ct < 5; ++ct) b0[ct] = Bp[(size_t)(ct * 32 + p2) * 64];
        }
        {
            short8 af = __builtin_bit_cast(short8, a1);
#pragma unroll
            for (int ct = 0; ct < 5; ++ct) {
                short8 bf = __builtin_bit_cast(short8, b1[ct]);
                acc[ct] = __builtin_amdgcn_mfma_f32_16x16x32_bf16(af, bf, acc[ct], 0, 0, 0);
            }
            a1 = A[p3 * 64];
#pragma unroll
            for (int ct = 0; ct < 5; ++ct) b1[ct] = Bp[(size_t)(ct * 32 + p3) * 64];
        }
    }

    float bv = bptr[0];
    float sc[5]; unsigned char ab[5];
#pragma unroll
    for (int ct = 0; ct < 5; ++ct) { sc[ct] = scale[ct * 16 + col]; ab[ct] = actB[ct * 16 + col]; }

    float contrib = 0.f;
#pragma unroll
    for (int reg = 0; reg < 4; ++reg) {
        int rl = q * 4 + reg;
        int row = rowbase + rl;
        float inv = 1.0f / fmaxf(sqrtf(xn2g[row]), 1e-8f);
        unsigned long long mask = masks[row];
        float v[5]; float lmax = -1e30f;
#pragma unroll
        for (int ct = 0; ct < 5; ++ct) {
            float lg = acc[ct][reg] * sc[ct] * inv + bv;   // w*cos + b
            v[ct] = ab[ct] ? lg : -1e30f;
            lmax = fmaxf(lmax, v[ct]);
        }
#pragma unroll
        for (int m = 1; m < 16; m <<= 1) lmax = fmaxf(lmax, __shfl_xor(lmax, m, 16));
        float es = 0.f;
#pragma unroll
        for (int ct = 0; ct < 5; ++ct) es += expf(v[ct] - lmax);
#pragma unroll
        for (int m = 1; m < 16; m <<= 1) es += __shfl_xor(es, m, 16);
        float lse = lmax + logf(es);
        float ps = 0.f;
#pragma unroll
        for (int ct = 0; ct < 5; ++ct) {
            int c = ct * 16 + col;
            bool pos = (c < 64) ? (((mask >> c) & 1ull) != 0ull)
                                : ((c == 64) ? (mask == 0ull) : false);
            ps += pos ? v[ct] : 0.f;
        }
#pragma unroll
        for (int m = 1; m < 16; m <<= 1) ps += __shfl_xor(ps, m, 16);
        float npos = mask ? (float)__popcll(mask) : 1.0f;
        float crow = ps - npos * lse;
        if (col == 0) contrib += crow;
    }
#pragma unroll
    for (int m = 1; m < 64; m <<= 1) contrib += __shfl_xor(contrib, m, 64);
    if (lane == 0) atomicAdd(wsum, contrib);
}

// ---- K4: loss = -sum(logp over positive pairs) / n_pairs ----
__global__ void k4_final(const unsigned* __restrict__ countsF,
                         const float* __restrict__ wsum,
                         float* __restrict__ out) {
    if (threadIdx.x == 0 && blockIdx.x == 0) {
        float np = 0.f;
        for (int c = 0; c < NC; ++c) np += (float)countsF[c];
        out[0] = -wsum[0] / np;
    }
}

extern "C" void kernel_launch(void* const* d_in, const int* in_sizes, int n_in,
                              void* d_out, int out_size, void* d_ws, size_t ws_size,
                              hipStream_t stream) {
    (void)in_sizes; (void)n_in; (void)out_size;
    const float* x = (const float*)d_in[0];
    const int* label = (const int*)d_in[1];
    const float* w = (const float*)d_in[2];
    const float* b = (const float*)d_in[3];

    char* ws = (char*)d_ws;
    float* scale = (float*)(ws + SCALE_B);
    unsigned char* actB = (unsigned char*)(ws + ACTB_B);
    float* wsum = (float*)(ws + WSUM_B);
    unsigned* countsF = (unsigned*)(ws + CNTF_B);
    unsigned* cntpart = (unsigned*)(ws + CNTP_B);
    unsigned long long* masks = (unsigned long long*)(ws + MASK_B);
    float* xn2g = (float*)(ws + XN2_B);
    unsigned short* lfrag = (unsigned short*)(ws + LFRAG_B);
    unsigned short* bfrag = (unsigned short*)(ws + BFRAG_B);
    unsigned short* xAfrag = (unsigned short*)(ws + XAF_B);
    unsigned short* xcol = (unsigned short*)(ws + XCOL_B);
    float* partial = (float*)(ws + PART_B);

    int kslices = 32;
    while (kslices > 8 && PART_B + (size_t)kslices * SLAB > ws_size) kslices >>= 1;

    hipLaunchKernelGGL(k01_prep, dim3(1024 + 256), dim3(256), 0, stream,
                       x, label, xAfrag, xcol, xn2g, masks, cntpart, lfrag);
    hipLaunchKernelGGL(k2_sums, dim3(16 * kslices), dim3(256), 0, stream,
                       xcol, lfrag, partial, kslices);
    hipLaunchKernelGGL(k2b_fuse, dim3(CPAD), dim3(1024), 0, stream,
                       w, cntpart, partial, kslices, bfrag, scale, actB, countsF, wsum);
    hipLaunchKernelGGL(k3_loss, dim3(NROWS / 64), dim3(256), 0, stream,
                       xAfrag, bfrag, xn2g, masks, actB, scale, b, wsum);
    hipLaunchKernelGGL(k4_final, dim3(1), dim3(64), 0, stream, countsF, wsum, (float*)d_out);
}